// Round 2
// baseline (67.356 us; speedup 1.0000x reference)
//
#include <hip/hip_runtime.h>
#include <math.h>

#define NCLS 10

// Closed-form "Pauli backprop" formulation, wave-per-image structure.
//
// e_w = sum over Pauli strings of (uniform coeff K) x (monomial in
// cA_w = cos(alpha_w), sA_w = sin(alpha_w)), alpha = pixel + vp0_w.
// K absorbs layer-0 RZ (phi), layer-1 RY (theta), and all CNOT signs.
//
// Structure: one image per 64-lane wave. Lane l owns patches
// {l, l+64, l+128} (+ l+192 if l<4). Features are consumed by the GEMV
// immediately in-register (chunk v == patch p on the same lane), so the
// kernel has NO LDS, NO __syncthreads, and every lane is live in every
// phase. Logit reduction = 6-step shfl_xor butterfly (result lands in
// all lanes), softmax computed redundantly per lane, predicated stores.

__global__ __launch_bounds__(256)
void quanv_fused(const float* __restrict__ x, const float* __restrict__ vp,
                 const float* __restrict__ W, const float* __restrict__ bias,
                 float* __restrict__ out) {
    const int l   = threadIdx.x & 63;
    const int wv  = threadIdx.x >> 6;
    const int img = blockIdx.x * 4 + wv;

    // ---- uniform Pauli-term coefficients (redundant per lane; vp uniform) ----
    float K[30];
    {
        float c1[4], s1[4], fx[4], fy[4];
        #pragma unroll
        for (int w = 0; w < 4; ++w) {
            __sincosf(vp[8 + w], &s1[w], &c1[w]);  // layer-1 RY, FULL angle
            __sincosf(vp[4 + w], &fy[w], &fx[w]);  // layer-0 RZ, FULL angle
        }
        K[0] = c1[0];
        K[1] = -s1[0] * fx[0] * fx[1];
        K[2] =  c1[0] * c1[1];
        K[3] = -c1[0] * s1[1] * fx[1] * fx[2];
        K[4] =  s1[0] * c1[1] * fy[0] * fy[1];
        K[5] =  s1[0] * s1[1] * fx[0] * fx[2];
        K[6]  =  c1[0] * c1[1] * c1[2];
        K[7]  = -c1[0] * c1[1] * s1[2] * fx[2] * fx[3];
        K[8]  =  c1[0] * s1[1] * c1[2] * fy[1] * fy[2];
        K[9]  =  c1[0] * s1[1] * s1[2] * fx[1] * fx[3];
        K[10] = -s1[0] * c1[1] * c1[2] * fx[0] * fx[1];
        K[11] = -s1[0] * c1[1] * s1[2] * fy[0] * fy[1] * fx[2] * fx[3];
        K[12] = -s1[0] * s1[1] * c1[2] * fy[0] * fy[2];
        K[13] = -s1[0] * s1[1] * s1[2] * fx[0] * fx[3];
        K[14] =  c1[0] * c1[1] * c1[2] * c1[3];
        K[15] = -c1[0] * c1[1] * c1[2] * s1[3] * fx[3];
        K[16] =  c1[0] * c1[1] * s1[2] * c1[3] * fy[2] * fy[3];
        K[17] =  c1[0] * c1[1] * s1[2] * s1[3] * fx[2];
        K[18] = -c1[0] * s1[1] * c1[2] * c1[3] * fx[1] * fx[2];
        K[19] = -c1[0] * s1[1] * c1[2] * s1[3] * fy[1] * fy[2] * fx[3];
        K[20] = -c1[0] * s1[1] * s1[2] * c1[3] * fy[1] * fy[3];
        K[21] = -c1[0] * s1[1] * s1[2] * s1[3] * fx[1];
        K[22] =  s1[0] * c1[1] * c1[2] * c1[3] * fy[0] * fy[1];
        K[23] =  s1[0] * c1[1] * c1[2] * s1[3] * fx[0] * fx[1] * fx[3];
        K[24] = -s1[0] * c1[1] * s1[2] * c1[3] * fx[0] * fx[1] * fy[2] * fy[3];
        K[25] =  s1[0] * c1[1] * s1[2] * s1[3] * fy[0] * fy[1] * fx[2];
        K[26] =  s1[0] * s1[1] * c1[2] * c1[3] * fx[0] * fx[2];
        K[27] =  s1[0] * s1[1] * c1[2] * s1[3] * fy[0] * fy[2] * fx[3];
        K[28] =  s1[0] * s1[1] * s1[2] * c1[3] * fy[0] * fy[3];
        K[29] =  s1[0] * s1[1] * s1[2] * s1[3] * fx[0];
    }
    const float v0 = vp[0], v1 = vp[1], v2 = vp[2], v3 = vp[3];

    float acc[NCLS];
    #pragma unroll
    for (int c = 0; c < NCLS; ++c) acc[c] = 0.0f;

    const float4* __restrict__ W4 = (const float4*)W;
    const float* __restrict__ xb0 = x + img * 784;

    #pragma unroll
    for (int r = 0; r < 4; ++r) {
        const int p = l + 64 * r;
        if (r < 3 || l < 4) {           // patch 192..195 tail on lanes 0..3
            const int i = p / 14;
            const int j = p - i * 14;
            const float* xb = xb0 + i * 56 + 2 * j;   // 2 rows of the patch
            const float2 A  = *(const float2*)xb;
            const float2 Bv = *(const float2*)(xb + 28);

            float cA[4], sA[4];
            __sincosf(A.x  + v0, &sA[0], &cA[0]);
            __sincosf(A.y  + v1, &sA[1], &cA[1]);
            __sincosf(Bv.x + v2, &sA[2], &cA[2]);
            __sincosf(Bv.y + v3, &sA[3], &cA[3]);

            const float s01 = sA[0] * sA[1];
            const float s23 = sA[2] * sA[3];
            const float e0 = K[0] * cA[0] + K[1] * s01;
            const float e1 = K[2] * cA[1] + K[3] * (cA[0] * sA[1] * sA[2])
                           + K[4] * s01   + K[5] * (sA[0] * sA[2]);
            const float e2 = K[6]  * (cA[0] * cA[2])
                           + K[7]  * (cA[1] * s23)
                           + K[8]  * (sA[1] * sA[2])
                           + K[9]  * (cA[0] * sA[1] * sA[3])
                           + K[10] * (s01 * cA[2])
                           + K[11] * (s01 * s23)
                           + K[12] * (sA[0] * cA[1] * sA[2])
                           + K[13] * (sA[0] * sA[3]);
            const float e3 = K[14] * (cA[1] * cA[3])
                           + K[15] * (cA[0] * cA[2] * sA[3])
                           + K[16] * (cA[0] * s23)
                           + K[17] * (cA[1] * sA[2])
                           + K[18] * (cA[0] * sA[1] * sA[2] * cA[3])
                           + K[19] * (sA[1] * s23)
                           + K[20] * (sA[1] * cA[2] * sA[3])
                           + K[21] * (cA[0] * sA[1])
                           + K[22] * (s01 * cA[3])
                           + K[23] * (s01 * cA[2] * sA[3])
                           + K[24] * (s01 * s23)
                           + K[25] * (s01 * sA[2])
                           + K[26] * (sA[0] * sA[2] * cA[3])
                           + K[27] * (sA[0] * cA[1] * sA[2] * sA[3])
                           + K[28] * (sA[0] * cA[1] * cA[2] * sA[3])
                           + K[29] * sA[0];

            // Fused GEMV: this lane owns feature chunk v == p.
            #pragma unroll
            for (int c = 0; c < NCLS; ++c) {
                const float4 w = W4[c * 196 + p];
                acc[c] += e0 * w.x + e1 * w.y + e2 * w.z + e3 * w.w;
            }
        }
    }

    // ---- per-class full-wave butterfly reduction (result in ALL lanes) ----
    #pragma unroll
    for (int c = 0; c < NCLS; ++c) {
        float v = acc[c];
        v += __shfl_xor(v, 1);
        v += __shfl_xor(v, 2);
        v += __shfl_xor(v, 4);
        v += __shfl_xor(v, 8);
        v += __shfl_xor(v, 16);
        v += __shfl_xor(v, 32);
        acc[c] = v + bias[c];
    }

    // ---- redundant per-lane log-softmax, predicated stores ----
    float m = acc[0];
    #pragma unroll
    for (int c = 1; c < NCLS; ++c) m = fmaxf(m, acc[c]);
    float ssum = 0.0f;
    #pragma unroll
    for (int c = 0; c < NCLS; ++c) ssum += __expf(acc[c] - m);
    const float lse = m + __logf(ssum);
    #pragma unroll
    for (int c = 0; c < NCLS; ++c)
        if (l == c) out[img * NCLS + c] = acc[c] - lse;
}

extern "C" void kernel_launch(void* const* d_in, const int* in_sizes, int n_in,
                              void* d_out, int out_size, void* d_ws, size_t ws_size,
                              hipStream_t stream) {
    const float* x  = (const float*)d_in[0];   // (2048, 28, 28)
    const float* vp = (const float*)d_in[1];   // (2, 2, 4)
    const float* W  = (const float*)d_in[2];   // (10, 784)
    const float* bb = (const float*)d_in[3];   // (10,)
    float* out = (float*)d_out;                // (2048, 10)

    quanv_fused<<<512, 256, 0, stream>>>(x, vp, W, bb, out);
}